// Round 8
// baseline (135.311 us; speedup 1.0000x reference)
//
#include <hip/hip_runtime.h>
#include <hip/hip_bf16.h>
#include <math.h>

// ---------------------------------------------------------------------------
// SentiGAT — round 7: decomposed pipeline, occupancy-sized GEMMs, bf16
// intermediates (hout, hg).
//  prep   : vvec + weight transposes
//  ow_pre : per-sample scores/alpha + input-space aggregate -> zcat bf16
//  A1     : hout(bf16) = zcat @ owWt^T + ow_b   (BM64xBN128, 896 blocks)
//  attn_x5: attn softmax + aligned + ind_norm -> x5b
//  C1/C3  : bf16 GEMMs (BM32xBN64, OUT bf16), C2/C4: 5-node GAT
//  D1     : split-K x4 fp32 partials, final2: reduce+relu+proj
// ---------------------------------------------------------------------------

#define B_SAMP 512

typedef short short8 __attribute__((ext_vector_type(8)));
typedef float floatx4 __attribute__((ext_vector_type(4)));

__device__ __forceinline__ float lrelu02(float x) { return x > 0.f ? x : 0.2f * x; }

__device__ __forceinline__ unsigned short cvt_bf16(float f) {
    union { float f; unsigned int u; } v; v.f = f;
    unsigned int u = v.u;
    return (unsigned short)((u + 0x7FFFu + ((u >> 16) & 1u)) >> 16);  // RNE
}
__device__ __forceinline__ float bf2f(unsigned short u) {
    union { unsigned int u; float f; } v; v.u = ((unsigned int)u) << 16;
    return v.f;
}

// ---------------- merged prep: ow_vvec + all weight transposes --------------
__global__ __launch_bounds__(256) void prep(
    const float* __restrict__ ow_W, const float* __restrict__ ow_asrc,
    const float* __restrict__ ow_adst,
    const float* __restrict__ g1_W, const float* __restrict__ g2_W,
    const float* __restrict__ m1_W,
    float* __restrict__ vg, unsigned short* __restrict__ owWt,
    unsigned short* __restrict__ g1Wt, unsigned short* __restrict__ g2Wt,
    unsigned short* __restrict__ m1Wt)
{
    __shared__ float T[32][33];
    const int tid = threadIdx.x;
    int bid = blockIdx.x;

    if (bid < 128) {
        const int lane = tid & 63;
        const int gw = bid * 4 + (tid >> 6);
        for (int idx = gw; idx < 2048; idx += 512) {
            int t = idx >> 9, k = idx & 511;
            const float* a = (t < 2) ? (ow_asrc + t * 512) : (ow_adst + (t - 2) * 512);
            const float* wr = ow_W + (size_t)k * 1024 + (t & 1) * 512;
            float s = 0.f;
#pragma unroll
            for (int j = 0; j < 8; ++j) s += wr[lane + 64 * j] * a[lane + 64 * j];
            for (int off = 32; off > 0; off >>= 1) s += __shfl_down(s, off, 64);
            if (lane == 0) vg[idx] = s;
        }
        return;
    }
    bid -= 128;
    const float* W; int ldw, K, Kpad, koff, ktiles; float scale; unsigned short* Wt;
    if (bid < 256)        { W = ow_W;       ldw = 1024; K = 512;  Kpad = 1024; koff = 0;   scale = 0.5f; Wt = owWt; ktiles = 16; }
    else if (bid < 512)   { bid -= 256;  W = ow_W + 512; ldw = 1024; K = 512;  Kpad = 1024; koff = 512; scale = 0.5f; Wt = owWt; ktiles = 16; }
    else if (bid < 784)   { bid -= 512;  W = g1_W; ldw = 512; K = 513;  Kpad = 544;  koff = 0; scale = 1.f; Wt = g1Wt; ktiles = 17; }
    else if (bid < 1040)  { bid -= 784;  W = g2_W; ldw = 512; K = 512;  Kpad = 512;  koff = 0; scale = 1.f; Wt = g2Wt; ktiles = 16; }
    else                  { bid -= 1040; W = m1_W; ldw = 512; K = 2560; Kpad = 2560; koff = 0; scale = 1.f; Wt = m1Wt; ktiles = 80; }
    const int k0 = (bid % ktiles) * 32;
    const int n0 = (bid / ktiles) * 32;
    {
        int kr = tid >> 3, nc = (tid & 7) * 4;
        float4 v = make_float4(0.f, 0.f, 0.f, 0.f);
        if (k0 + kr < K) v = *(const float4*)(W + (size_t)(k0 + kr) * ldw + n0 + nc);
        T[nc + 0][kr] = v.x * scale; T[nc + 1][kr] = v.y * scale;
        T[nc + 2][kr] = v.z * scale; T[nc + 3][kr] = v.w * scale;
    }
    __syncthreads();
    {
        int nr = tid >> 3, kc = (tid & 7) * 4;
        ushort4 w;
        w.x = cvt_bf16(T[nr][kc + 0]);
        w.y = cvt_bf16(T[nr][kc + 1]);
        w.z = cvt_bf16(T[nr][kc + 2]);
        w.w = cvt_bf16(T[nr][kc + 3]);
        *(ushort4*)(Wt + (size_t)(n0 + nr) * Kpad + koff + k0 + kc) = w;
    }
}

// ---------------- ow_pre: scores + alpha + input-space aggregate ------------
__global__ __launch_bounds__(256) void ow_pre(
    const float* __restrict__ wf, const float* __restrict__ of,
    const float* __restrict__ vg,
    unsigned short* __restrict__ zcat)   // [B*28][1024] bf16
{
    const int b = blockIdx.x;
    __shared__ float Xs[28][512];
    __shared__ float ss[28][2], sd[28][2];
    __shared__ float alpha[16][2][13];

    const int tid = threadIdx.x;
    const int lane = tid & 63;
    const int wid = tid >> 6;

    for (int idx = tid; idx < 28 * 128; idx += 256) {
        int n = idx >> 7, c = (idx & 127) * 4;
        const float* src = (n < 12) ? (wf + ((size_t)b * 12 + n) * 512)
                                    : (of + ((size_t)b * 16 + (n - 12)) * 512);
        *(float4*)&Xs[n][c] = *(const float4*)(src + c);
    }
    __syncthreads();

    for (int p = wid; p < 112; p += 4) {
        int n = p >> 2, t = p & 3;
        const float* vv = vg + t * 512;
        float s = 0.f;
#pragma unroll
        for (int j = 0; j < 8; ++j) s += Xs[n][lane + 64 * j] * vv[lane + 64 * j];
        for (int off = 32; off > 0; off >>= 1) s += __shfl_down(s, off, 64);
        if (lane == 0) { if (t < 2) ss[n][t] = s; else sd[n][t - 2] = s; }
    }
    __syncthreads();

    if (tid < 32) {
        int w = tid >> 1, h = tid & 1;
        float sdv = sd[12 + w][h];
        float e[13], mx = -1e30f;
        for (int j = 0; j < 12; ++j) { e[j] = lrelu02(ss[j][h] + sdv); mx = fmaxf(mx, e[j]); }
        e[12] = lrelu02(ss[12 + w][h] + sdv); mx = fmaxf(mx, e[12]);
        float den = 0.f;
        for (int j = 0; j < 13; ++j) { e[j] = expf(e[j] - mx); den += e[j]; }
        float inv = 1.f / den;
        for (int j = 0; j < 13; ++j) alpha[w][h][j] = e[j] * inv;
    }
    __syncthreads();

    unsigned short* zb = zcat + (size_t)b * 28 * 1024;
    for (int idx = tid; idx < 12 * 1024; idx += 256) {
        int n = idx >> 10, d = idx & 511;
        zb[idx] = cvt_bf16(Xs[n][d]);
    }
    for (int c = tid; c < 1024; c += 256) {
        int h = c >> 9, d = c & 511;
        float xr[12];
#pragma unroll
        for (int j = 0; j < 12; ++j) xr[j] = Xs[j][d];
#pragma unroll 4
        for (int w = 0; w < 16; ++w) {
            float a = alpha[w][h][12] * Xs[12 + w][d];
#pragma unroll
            for (int j = 0; j < 12; ++j) a += alpha[w][h][j] * xr[j];
            zb[(size_t)(12 + w) * 1024 + c] = cvt_bf16(a);
        }
    }
}

// ---------------- GEMM v3: dbuf pipeline, wave-grid + bf16-out options ------
// C = A(bf16)[M][lda] @ Bt(bf16)[N][ldbt]^T (+bias)(+relu); 256 threads.
// waves arranged WGM x (4/WGM). grid: x=M-tiles, y=N-tiles, z=split-K.
template <int BM, int BN, int WGM, int RELU, int SPLITK, int OBF16>
__global__ __launch_bounds__(256) void gemm_v3(
    const unsigned short* __restrict__ A, int lda,
    const unsigned short* __restrict__ Bt, int ldbt,
    void* __restrict__ Cv, int ldc,
    int M, int N, int K,
    const float* __restrict__ bias)
{
    constexpr int WGN = 4 / WGM;
    constexpr int WM = BM / WGM, WN = BN / WGN;
    constexpr int MF = WM / 16, NF = WN / 16;
    constexpr int CA = (BM * 4 + 255) / 256, CB = (BN * 4 + 255) / 256;

    __shared__ unsigned short As[2][BM][40];
    __shared__ unsigned short Bs[2][BN][40];

    const int tid = threadIdx.x;
    const int m0 = blockIdx.x * BM;
    const int n0 = blockIdx.y * BN;
    const int lane = tid & 63;
    const int wid = tid >> 6;
    const int wm = (wid % WGM) * WM;
    const int wn = (wid / WGM) * WN;
    const int fr = lane & 15;
    const int kq = (lane >> 4) * 8;

    const int kchunk = K / SPLITK;
    const int kbeg = (SPLITK > 1) ? blockIdx.z * kchunk : 0;
    const int kend = kbeg + kchunk;
    float* Cf = (float*)Cv;
    unsigned short* Cb = (unsigned short*)Cv;
    if (SPLITK > 1) Cf += (size_t)blockIdx.z * M * ldc;

    short8 ra[CA], rb[CB];
#define LOADAB(K0)                                                                       \
    do {                                                                                 \
        _Pragma("unroll")                                                                \
        for (int c = 0; c < CA; ++c) {                                                   \
            int id = tid + c * 256;                                                      \
            if (BM * 4 % 256 == 0 || id < BM * 4)                                        \
                ra[c] = *(const short8*)(A + (size_t)(m0 + (id >> 2)) * lda + (K0) + (id & 3) * 8); \
        }                                                                                \
        _Pragma("unroll")                                                                \
        for (int c = 0; c < CB; ++c) {                                                   \
            int id = tid + c * 256;                                                      \
            if (BN * 4 % 256 == 0 || id < BN * 4)                                        \
                rb[c] = *(const short8*)(Bt + (size_t)(n0 + (id >> 2)) * ldbt + (K0) + (id & 3) * 8); \
        }                                                                                \
    } while (0)

    LOADAB(kbeg);

    floatx4 acc[MF][NF];
#pragma unroll
    for (int i = 0; i < MF; ++i)
#pragma unroll
        for (int j = 0; j < NF; ++j) acc[i][j] = (floatx4){0.f, 0.f, 0.f, 0.f};

    int t = 0;
    for (int k0 = kbeg; k0 < kend; k0 += 32, t ^= 1) {
#pragma unroll
        for (int c = 0; c < CA; ++c) {
            int id = tid + c * 256;
            if (BM * 4 % 256 == 0 || id < BM * 4)
                *(short8*)&As[t][id >> 2][(id & 3) * 8] = ra[c];
        }
#pragma unroll
        for (int c = 0; c < CB; ++c) {
            int id = tid + c * 256;
            if (BN * 4 % 256 == 0 || id < BN * 4)
                *(short8*)&Bs[t][id >> 2][(id & 3) * 8] = rb[c];
        }
        __syncthreads();
        if (k0 + 32 < kend) LOADAB(k0 + 32);   // prefetch flies under ds_read+MFMA

        short8 af[MF], bw[NF];
#pragma unroll
        for (int i = 0; i < MF; ++i)
            af[i] = *(const short8*)&As[t][wm + i * 16 + fr][kq];
#pragma unroll
        for (int j = 0; j < NF; ++j)
            bw[j] = *(const short8*)&Bs[t][wn + j * 16 + fr][kq];
#pragma unroll
        for (int i = 0; i < MF; ++i)
#pragma unroll
            for (int j = 0; j < NF; ++j)
                acc[i][j] = __builtin_amdgcn_mfma_f32_16x16x32_bf16(
                    af[i], bw[j], acc[i][j], 0, 0, 0);
        // single barrier per K-step: buf t rewritten only after next sync
    }
#undef LOADAB

    const int fq = lane >> 4;
#pragma unroll
    for (int i = 0; i < MF; ++i) {
#pragma unroll
        for (int j = 0; j < NF; ++j) {
#pragma unroll
            for (int q = 0; q < 4; ++q) {
                int row = m0 + wm + i * 16 + fq * 4 + q;
                int col = n0 + wn + j * 16 + fr;
                float v = acc[i][j][q];
                if (SPLITK == 1 && bias) v += bias[col];
                if (RELU) v = fmaxf(v, 0.f);
                if (OBF16) Cb[(size_t)row * ldc + col] = cvt_bf16(v);
                else       Cf[(size_t)row * ldc + col] = v;
            }
        }
    }
}

// ---------------- attn + ind_norm fused: hout(bf16) -> x5b rows -------------
__global__ __launch_bounds__(256) void attn_x5(
    const unsigned short* __restrict__ hout,
    const float* __restrict__ tf, const float* __restrict__ im,
    const float* __restrict__ it, const float* __restrict__ fa,
    unsigned short* __restrict__ x5)
{
    const int b = blockIdx.x;
    __shared__ float uo[12][520];
    __shared__ float uw[16][520];
    __shared__ float S[12][16];
    __shared__ float w16[16];
    __shared__ float al[512];

    const int tid = threadIdx.x;
    const int lane = tid & 63;
    const int wid = tid >> 6;
    const unsigned short* hb = hout + (size_t)b * 28 * 512;

    for (int idx = tid; idx < 28 * 64; idx += 256) {
        int n = idx >> 6, c = (idx & 63) * 8;
        short8 v = *(const short8*)(hb + (size_t)n * 512 + c);
        float* row = (n < 12) ? &uo[n][c] : &uw[n - 12][c];
#pragma unroll
        for (int j = 0; j < 8; ++j) row[j] = bf2f((unsigned short)v[j]);
    }
    __syncthreads();

    for (int p = wid; p < 192; p += 4) {   // wave-parallel 12x16 dots
        int i = p >> 4, j = p & 15;
        const float* ua = &uo[i][lane * 8];
        const float* uc = &uw[j][lane * 8];
        float s = 0.f;
#pragma unroll
        for (int d = 0; d < 8; ++d) s += ua[d] * uc[d];
        for (int off = 32; off > 0; off >>= 1) s += __shfl_down(s, off, 64);
        if (lane == 0) S[i][j] = s;
    }
    __syncthreads();

    if (tid < 12) {
        float mx = -1e30f;
        for (int j = 0; j < 16; ++j) mx = fmaxf(mx, S[tid][j]);
        float den = 0.f;
        for (int j = 0; j < 16; ++j) { float p = expf(S[tid][j] - mx); S[tid][j] = p; den += p; }
        float inv = 1.f / den;
        for (int j = 0; j < 16; ++j) S[tid][j] *= inv;
    }
    __syncthreads();

    if (tid < 16) {
        float s = 0.f;
        for (int i = 0; i < 12; ++i) s += S[i][tid];
        w16[tid] = s * (1.f / 12.f);
    }
    __syncthreads();

    for (int d = tid; d < 512; d += 256) {
        float s = 0.f;
#pragma unroll
        for (int j = 0; j < 16; ++j) s += w16[j] * uw[j][d];
        al[d] = s;
    }
    __syncthreads();

    for (int f = wid; f < 5; f += 4) {
        const float* src = (f == 0) ? tf : (f == 1) ? im : (f == 2) ? it : (f == 3) ? fa : nullptr;
        float vals[8];
        float sum = 0.f, sq = 0.f;
#pragma unroll
        for (int j = 0; j < 8; ++j) {
            float v = (f < 4) ? src[(size_t)b * 512 + lane + 64 * j] : al[lane + 64 * j];
            vals[j] = v;
            sum += v;
            sq += v * v;
        }
#pragma unroll
        for (int off = 32; off > 0; off >>= 1) {
            sum += __shfl_xor(sum, off, 64);
            sq  += __shfl_xor(sq,  off, 64);
        }
        float v = (sum != 0.f) ? 1.f : 0.f;
        float nrm = fmaxf(sqrtf(sq + v * v), 1e-12f);
        float inv = 1.f / nrm;
        unsigned short* dst = x5 + ((size_t)b * 5 + f) * 544;
#pragma unroll
        for (int j = 0; j < 8; ++j) dst[lane + 64 * j] = cvt_bf16(vals[j] * inv);
        if (lane == 0) dst[512] = cvt_bf16(v * inv);
        else if (lane < 32) dst[512 + lane] = 0;
    }
}

// ---------------- C2/C4: 5-node complete-graph GAT (bf16 in/out) ------------
template <int RELU>
__global__ __launch_bounds__(256) void g5_gat(
    const unsigned short* __restrict__ Hg,
    const float* __restrict__ asrc, const float* __restrict__ adst,
    const float* __restrict__ bias, unsigned short* __restrict__ outp)
{
    const int b = blockIdx.x;
    __shared__ float ss[5], sd[5];
    __shared__ float alpha[5][5];

    const int tid = threadIdx.x;
    const int lane = tid & 63;
    const int wave = tid >> 6;
    const unsigned short* Hb = Hg + (size_t)b * 5 * 512;

    for (int p = wave; p < 10; p += 4) {
        int n = p >> 1, ty = p & 1;
        const unsigned short* hv = Hb + n * 512;
        const float* av = ty ? adst : asrc;
        float s = 0.f;
#pragma unroll
        for (int j = 0; j < 8; ++j) s += bf2f(hv[lane + 64 * j]) * av[lane + 64 * j];
        for (int off = 32; off > 0; off >>= 1) s += __shfl_down(s, off, 64);
        if (lane == 0) { if (ty) sd[n] = s; else ss[n] = s; }
    }
    __syncthreads();

    if (tid < 5) {
        int dn = tid;
        float e[5];
        float mx = -1e30f;
        for (int s = 0; s < 5; ++s) {
            e[s] = lrelu02(ss[s] + sd[dn]);
            mx = fmaxf(mx, e[s]);
        }
        float den = 0.f;
        for (int s = 0; s < 5; ++s) { e[s] = expf(e[s] - mx); den += e[s]; }
        float inv = 1.f / den;
        for (int s = 0; s < 5; ++s) alpha[dn][s] = e[s] * inv;
    }
    __syncthreads();

    for (int d = tid; d < 512; d += 256) {
        float h0 = bf2f(Hb[0 * 512 + d]), h1 = bf2f(Hb[1 * 512 + d]), h2 = bf2f(Hb[2 * 512 + d]);
        float h3 = bf2f(Hb[3 * 512 + d]), h4 = bf2f(Hb[4 * 512 + d]);
        float bd = bias[d];
#pragma unroll
        for (int dn = 0; dn < 5; ++dn) {
            float v = alpha[dn][0] * h0 + alpha[dn][1] * h1 + alpha[dn][2] * h2 +
                      alpha[dn][3] * h3 + alpha[dn][4] * h4 + bd;
            if (RELU) v = fmaxf(v, 0.f);
            outp[((size_t)b * 5 + dn) * 512 + d] = cvt_bf16(v);
        }
    }
}

// ---------------- final: relu(sum split-K parts + b1) @ m2 + b2 -------------
__global__ __launch_bounds__(64) void final2(
    const float* __restrict__ parts, const float* __restrict__ b1,
    const float* __restrict__ w, const float* __restrict__ bvec,
    float* __restrict__ out)
{
    const int b = blockIdx.x;
    const int lane = threadIdx.x;
    float a0 = 0.f, a1 = 0.f, a2 = 0.f;
#pragma unroll
    for (int j = 0; j < 8; ++j) {
        int d = lane + 64 * j;
        size_t o = (size_t)b * 512 + d;
        float x = parts[o] + parts[262144 + o] + parts[524288 + o] + parts[786432 + o] + b1[d];
        x = fmaxf(x, 0.f);
        a0 += x * w[d * 3 + 0];
        a1 += x * w[d * 3 + 1];
        a2 += x * w[d * 3 + 2];
    }
    for (int off = 32; off > 0; off >>= 1) {
        a0 += __shfl_down(a0, off, 64);
        a1 += __shfl_down(a1, off, 64);
        a2 += __shfl_down(a2, off, 64);
    }
    if (lane == 0) {
        out[b * 3 + 0] = a0 + bvec[0];
        out[b * 3 + 1] = a1 + bvec[1];
        out[b * 3 + 2] = a2 + bvec[2];
    }
}

extern "C" void kernel_launch(void* const* d_in, const int* in_sizes, int n_in,
                              void* d_out, int out_size, void* d_ws, size_t ws_size,
                              hipStream_t stream) {
    const float* text   = (const float*)d_in[0];
    const float* image  = (const float*)d_in[1];
    const float* imgtxt = (const float*)d_in[2];
    const float* face   = (const float*)d_in[3];
    const float* word   = (const float*)d_in[4];
    const float* obj    = (const float*)d_in[5];
    const float* ow_W    = (const float*)d_in[6];
    const float* ow_asrc = (const float*)d_in[7];
    const float* ow_adst = (const float*)d_in[8];
    const float* ow_b    = (const float*)d_in[9];
    const float* g1_W    = (const float*)d_in[10];
    const float* g1_asrc = (const float*)d_in[11];
    const float* g1_adst = (const float*)d_in[12];
    const float* g1_b    = (const float*)d_in[13];
    const float* g2_W    = (const float*)d_in[14];
    const float* g2_asrc = (const float*)d_in[15];
    const float* g2_adst = (const float*)d_in[16];
    const float* g2_b    = (const float*)d_in[17];
    const float* m1_W    = (const float*)d_in[18];
    const float* m1_b    = (const float*)d_in[19];
    const float* m2_W    = (const float*)d_in[20];
    const float* m2_b    = (const float*)d_in[21];

    float* ws = (float*)d_ws;
    float* vg = ws;                                         // 2048 f
    float* hidp = ws + 2048;                                // 4x512x512 f
    unsigned short* owWt = (unsigned short*)(hidp + 1048576); // 512x1024
    unsigned short* g1Wt = owWt + 524288;                   // 512x544
    unsigned short* g2Wt = g1Wt + 278528;                   // 512x512
    unsigned short* m1Wt = g2Wt + 262144;                   // 512x2560
    unsigned short* zcat = m1Wt + 1310720;                  // 14336x1024
    unsigned short* houtb = zcat + 14680064;                // 14336x512
    unsigned short* x5b  = houtb + 7340032;                 // 2560x544
    unsigned short* h1b  = x5b + 1392640;                   // 2560x512
    unsigned short* fsb  = h1b + 1310720;                   // 2560x512
    unsigned short* hgb  = fsb + 1310720;                   // 2560x512

    // prep: vvec + all weight transposes
    prep<<<2448, 256, 0, stream>>>(ow_W, ow_asrc, ow_adst, g1_W, g2_W, m1_W,
                                   vg, owWt, g1Wt, g2Wt, m1Wt);

    // stage A
    ow_pre<<<B_SAMP, 256, 0, stream>>>(word, obj, vg, zcat);
    gemm_v3<64, 128, 2, 0, 1, 1><<<dim3(224, 4), 256, 0, stream>>>(
        zcat, 1024, owWt, 1024, houtb, 512, 14336, 512, 1024, ow_b);
    attn_x5<<<B_SAMP, 256, 0, stream>>>(houtb, text, image, imgtxt, face, x5b);

    // stage C
    gemm_v3<32, 64, 1, 0, 1, 1><<<dim3(80, 8), 256, 0, stream>>>(
        x5b, 544, g1Wt, 544, hgb, 512, 2560, 512, 544, nullptr);
    g5_gat<1><<<B_SAMP, 256, 0, stream>>>(hgb, g1_asrc, g1_adst, g1_b, h1b);
    gemm_v3<32, 64, 1, 0, 1, 1><<<dim3(80, 8), 256, 0, stream>>>(
        h1b, 512, g2Wt, 512, hgb, 512, 2560, 512, 512, nullptr);
    g5_gat<0><<<B_SAMP, 256, 0, stream>>>(hgb, g2_asrc, g2_adst, g2_b, fsb);

    // stage D (fsb viewed as [512][2560])
    gemm_v3<32, 64, 1, 0, 4, 0><<<dim3(16, 8, 4), 256, 0, stream>>>(
        fsb, 2560, m1Wt, 2560, hidp, 512, 512, 512, 2560, nullptr);
    final2<<<B_SAMP, 64, 0, stream>>>(hidp, m1_b, m2_W, m2_b, (float*)d_out);
}

// Round 9
// 130.673 us; speedup vs baseline: 1.0355x; 1.0355x over previous
//
#include <hip/hip_runtime.h>
#include <hip/hip_bf16.h>
#include <math.h>

// ---------------------------------------------------------------------------
// SentiGAT — round 8: A1 rebuilt as m97-style global_load_lds GEMM
// (128x128 tile, BK=32, linear LDS, dbuf, 1 barrier/K-step); C/D GEMMs back
// to 64x64 WGM=2. Everything else as round 7.
// ---------------------------------------------------------------------------

#define B_SAMP 512

typedef short short8 __attribute__((ext_vector_type(8)));
typedef float floatx4 __attribute__((ext_vector_type(4)));

__device__ __forceinline__ float lrelu02(float x) { return x > 0.f ? x : 0.2f * x; }

__device__ __forceinline__ unsigned short cvt_bf16(float f) {
    union { float f; unsigned int u; } v; v.f = f;
    unsigned int u = v.u;
    return (unsigned short)((u + 0x7FFFu + ((u >> 16) & 1u)) >> 16);  // RNE
}
__device__ __forceinline__ float bf2f(unsigned short u) {
    union { unsigned int u; float f; } v; v.u = ((unsigned int)u) << 16;
    return v.f;
}
__device__ __forceinline__ void gload_lds16(const unsigned short* g, unsigned short* l) {
    __builtin_amdgcn_global_load_lds(
        (const __attribute__((address_space(1))) void*)g,
        (__attribute__((address_space(3))) void*)l, 16, 0, 0);
}

// ---------------- merged prep: ow_vvec + all weight transposes --------------
__global__ __launch_bounds__(256) void prep(
    const float* __restrict__ ow_W, const float* __restrict__ ow_asrc,
    const float* __restrict__ ow_adst,
    const float* __restrict__ g1_W, const float* __restrict__ g2_W,
    const float* __restrict__ m1_W,
    float* __restrict__ vg, unsigned short* __restrict__ owWt,
    unsigned short* __restrict__ g1Wt, unsigned short* __restrict__ g2Wt,
    unsigned short* __restrict__ m1Wt)
{
    __shared__ float T[32][33];
    const int tid = threadIdx.x;
    int bid = blockIdx.x;

    if (bid < 128) {
        const int lane = tid & 63;
        const int gw = bid * 4 + (tid >> 6);
        for (int idx = gw; idx < 2048; idx += 512) {
            int t = idx >> 9, k = idx & 511;
            const float* a = (t < 2) ? (ow_asrc + t * 512) : (ow_adst + (t - 2) * 512);
            const float* wr = ow_W + (size_t)k * 1024 + (t & 1) * 512;
            float s = 0.f;
#pragma unroll
            for (int j = 0; j < 8; ++j) s += wr[lane + 64 * j] * a[lane + 64 * j];
            for (int off = 32; off > 0; off >>= 1) s += __shfl_down(s, off, 64);
            if (lane == 0) vg[idx] = s;
        }
        return;
    }
    bid -= 128;
    const float* W; int ldw, K, Kpad, koff, ktiles; float scale; unsigned short* Wt;
    if (bid < 256)        { W = ow_W;       ldw = 1024; K = 512;  Kpad = 1024; koff = 0;   scale = 0.5f; Wt = owWt; ktiles = 16; }
    else if (bid < 512)   { bid -= 256;  W = ow_W + 512; ldw = 1024; K = 512;  Kpad = 1024; koff = 512; scale = 0.5f; Wt = owWt; ktiles = 16; }
    else if (bid < 784)   { bid -= 512;  W = g1_W; ldw = 512; K = 513;  Kpad = 544;  koff = 0; scale = 1.f; Wt = g1Wt; ktiles = 17; }
    else if (bid < 1040)  { bid -= 784;  W = g2_W; ldw = 512; K = 512;  Kpad = 512;  koff = 0; scale = 1.f; Wt = g2Wt; ktiles = 16; }
    else                  { bid -= 1040; W = m1_W; ldw = 512; K = 2560; Kpad = 2560; koff = 0; scale = 1.f; Wt = m1Wt; ktiles = 80; }
    const int k0 = (bid % ktiles) * 32;
    const int n0 = (bid / ktiles) * 32;
    {
        int kr = tid >> 3, nc = (tid & 7) * 4;
        float4 v = make_float4(0.f, 0.f, 0.f, 0.f);
        if (k0 + kr < K) v = *(const float4*)(W + (size_t)(k0 + kr) * ldw + n0 + nc);
        T[nc + 0][kr] = v.x * scale; T[nc + 1][kr] = v.y * scale;
        T[nc + 2][kr] = v.z * scale; T[nc + 3][kr] = v.w * scale;
    }
    __syncthreads();
    {
        int nr = tid >> 3, kc = (tid & 7) * 4;
        ushort4 w;
        w.x = cvt_bf16(T[nr][kc + 0]);
        w.y = cvt_bf16(T[nr][kc + 1]);
        w.z = cvt_bf16(T[nr][kc + 2]);
        w.w = cvt_bf16(T[nr][kc + 3]);
        *(ushort4*)(Wt + (size_t)(n0 + nr) * Kpad + koff + k0 + kc) = w;
    }
}

// ---------------- ow_pre: scores + alpha + input-space aggregate ------------
__global__ __launch_bounds__(256) void ow_pre(
    const float* __restrict__ wf, const float* __restrict__ of,
    const float* __restrict__ vg,
    unsigned short* __restrict__ zcat)   // [B*28][1024] bf16
{
    const int b = blockIdx.x;
    __shared__ float Xs[28][512];
    __shared__ float ss[28][2], sd[28][2];
    __shared__ float alpha[16][2][13];

    const int tid = threadIdx.x;
    const int lane = tid & 63;
    const int wid = tid >> 6;

    for (int idx = tid; idx < 28 * 128; idx += 256) {
        int n = idx >> 7, c = (idx & 127) * 4;
        const float* src = (n < 12) ? (wf + ((size_t)b * 12 + n) * 512)
                                    : (of + ((size_t)b * 16 + (n - 12)) * 512);
        *(float4*)&Xs[n][c] = *(const float4*)(src + c);
    }
    __syncthreads();

    for (int p = wid; p < 112; p += 4) {
        int n = p >> 2, t = p & 3;
        const float* vv = vg + t * 512;
        float s = 0.f;
#pragma unroll
        for (int j = 0; j < 8; ++j) s += Xs[n][lane + 64 * j] * vv[lane + 64 * j];
        for (int off = 32; off > 0; off >>= 1) s += __shfl_down(s, off, 64);
        if (lane == 0) { if (t < 2) ss[n][t] = s; else sd[n][t - 2] = s; }
    }
    __syncthreads();

    if (tid < 32) {
        int w = tid >> 1, h = tid & 1;
        float sdv = sd[12 + w][h];
        float e[13], mx = -1e30f;
        for (int j = 0; j < 12; ++j) { e[j] = lrelu02(ss[j][h] + sdv); mx = fmaxf(mx, e[j]); }
        e[12] = lrelu02(ss[12 + w][h] + sdv); mx = fmaxf(mx, e[12]);
        float den = 0.f;
        for (int j = 0; j < 13; ++j) { e[j] = expf(e[j] - mx); den += e[j]; }
        float inv = 1.f / den;
        for (int j = 0; j < 13; ++j) alpha[w][h][j] = e[j] * inv;
    }
    __syncthreads();

    unsigned short* zb = zcat + (size_t)b * 28 * 1024;
    for (int idx = tid; idx < 12 * 1024; idx += 256) {
        int n = idx >> 10, d = idx & 511;
        zb[idx] = cvt_bf16(Xs[n][d]);
    }
    for (int c = tid; c < 1024; c += 256) {
        int h = c >> 9, d = c & 511;
        float xr[12];
#pragma unroll
        for (int j = 0; j < 12; ++j) xr[j] = Xs[j][d];
#pragma unroll 4
        for (int w = 0; w < 16; ++w) {
            float a = alpha[w][h][12] * Xs[12 + w][d];
#pragma unroll
            for (int j = 0; j < 12; ++j) a += alpha[w][h][j] * xr[j];
            zb[(size_t)(12 + w) * 1024 + c] = cvt_bf16(a);
        }
    }
}

// ---------------- A1: m97-style GEMM with global_load_lds -------------------
// C(bf16)[M][ldc] = A(bf16)[M][lda] @ Bt(bf16)[N][ldbt]^T + bias
// 128x128 tile, BK=32, linear LDS [128][32], dbuf, 1 barrier/K-step.
__global__ __launch_bounds__(256) void gemm_glds(
    const unsigned short* __restrict__ A, int lda,
    const unsigned short* __restrict__ Bt, int ldbt,
    unsigned short* __restrict__ C, int ldc,
    int K, const float* __restrict__ bias)
{
    __shared__ unsigned short As[2][128][32];
    __shared__ unsigned short Bs[2][128][32];

    const int tid = threadIdx.x;
    const int lane = tid & 63;
    const int wid = tid >> 6;
    const int m0 = blockIdx.x * 128;
    const int n0 = blockIdx.y * 128;

    // staging: wave wid covers rows [32*wid, 32*wid+32) of both A and B,
    // two 16-row global_load_lds instructions each (lane l -> row +l/4, seg l%4)
    const int srow = lane >> 2;
    const int sseg = (lane & 3) * 8;
    const unsigned short* ga = A + (size_t)(m0 + wid * 32 + srow) * lda + sseg;
    const unsigned short* gb = Bt + (size_t)(n0 + wid * 32 + srow) * ldbt + sseg;
    const size_t a16 = (size_t)16 * lda, b16 = (size_t)16 * ldbt;

#define STAGE(t, K0)                                              \
    do {                                                          \
        gload_lds16(ga + (K0), &As[t][wid * 32][0]);              \
        gload_lds16(ga + (K0) + a16, &As[t][wid * 32 + 16][0]);   \
        gload_lds16(gb + (K0), &Bs[t][wid * 32][0]);              \
        gload_lds16(gb + (K0) + b16, &Bs[t][wid * 32 + 16][0]);   \
    } while (0)

    const int wm = (wid & 1) * 64;
    const int wn = (wid >> 1) * 64;
    const int fr = lane & 15;
    const int kq = (lane >> 4) * 8;

    floatx4 acc[4][4];
#pragma unroll
    for (int i = 0; i < 4; ++i)
#pragma unroll
        for (int j = 0; j < 4; ++j) acc[i][j] = (floatx4){0.f, 0.f, 0.f, 0.f};

    STAGE(0, 0);
    __syncthreads();   // drains vmcnt: buf0 ready

    int t = 0;
    for (int k0 = 0; k0 < K; k0 += 32, t ^= 1) {
        if (k0 + 32 < K) STAGE(t ^ 1, k0 + 32);   // flies under ds_read+MFMA

        short8 af[4], bw[4];
#pragma unroll
        for (int i = 0; i < 4; ++i)
            af[i] = *(const short8*)&As[t][wm + i * 16 + fr][kq];
#pragma unroll
        for (int j = 0; j < 4; ++j)
            bw[j] = *(const short8*)&Bs[t][wn + j * 16 + fr][kq];
#pragma unroll
        for (int i = 0; i < 4; ++i)
#pragma unroll
            for (int j = 0; j < 4; ++j)
                acc[i][j] = __builtin_amdgcn_mfma_f32_16x16x32_bf16(
                    af[i], bw[j], acc[i][j], 0, 0, 0);
        __syncthreads();   // drains next-tile loads + protects buf swap
    }
#undef STAGE

    const int fq = lane >> 4;
#pragma unroll
    for (int i = 0; i < 4; ++i) {
#pragma unroll
        for (int j = 0; j < 4; ++j) {
#pragma unroll
            for (int q = 0; q < 4; ++q) {
                int row = m0 + wm + i * 16 + fq * 4 + q;
                int col = n0 + wn + j * 16 + fr;
                C[(size_t)row * ldc + col] = cvt_bf16(acc[i][j][q] + bias[col]);
            }
        }
    }
}

// ---------------- GEMM v3: dbuf pipeline (reg-staged), 64x64 ----------------
template <int BM, int BN, int WGM, int RELU, int SPLITK, int OBF16>
__global__ __launch_bounds__(256) void gemm_v3(
    const unsigned short* __restrict__ A, int lda,
    const unsigned short* __restrict__ Bt, int ldbt,
    void* __restrict__ Cv, int ldc,
    int M, int N, int K,
    const float* __restrict__ bias)
{
    constexpr int WGN = 4 / WGM;
    constexpr int WM = BM / WGM, WN = BN / WGN;
    constexpr int MF = WM / 16, NF = WN / 16;
    constexpr int CA = (BM * 4 + 255) / 256, CB = (BN * 4 + 255) / 256;

    __shared__ unsigned short As[2][BM][40];
    __shared__ unsigned short Bs[2][BN][40];

    const int tid = threadIdx.x;
    const int m0 = blockIdx.x * BM;
    const int n0 = blockIdx.y * BN;
    const int lane = tid & 63;
    const int wid = tid >> 6;
    const int wm = (wid % WGM) * WM;
    const int wn = (wid / WGM) * WN;
    const int fr = lane & 15;
    const int kq = (lane >> 4) * 8;

    const int kchunk = K / SPLITK;
    const int kbeg = (SPLITK > 1) ? blockIdx.z * kchunk : 0;
    const int kend = kbeg + kchunk;
    float* Cf = (float*)Cv;
    unsigned short* Cb = (unsigned short*)Cv;
    if (SPLITK > 1) Cf += (size_t)blockIdx.z * M * ldc;

    short8 ra[CA], rb[CB];
#define LOADAB(K0)                                                                       \
    do {                                                                                 \
        _Pragma("unroll")                                                                \
        for (int c = 0; c < CA; ++c) {                                                   \
            int id = tid + c * 256;                                                      \
            if (BM * 4 % 256 == 0 || id < BM * 4)                                        \
                ra[c] = *(const short8*)(A + (size_t)(m0 + (id >> 2)) * lda + (K0) + (id & 3) * 8); \
        }                                                                                \
        _Pragma("unroll")                                                                \
        for (int c = 0; c < CB; ++c) {                                                   \
            int id = tid + c * 256;                                                      \
            if (BN * 4 % 256 == 0 || id < BN * 4)                                        \
                rb[c] = *(const short8*)(Bt + (size_t)(n0 + (id >> 2)) * ldbt + (K0) + (id & 3) * 8); \
        }                                                                                \
    } while (0)

    LOADAB(kbeg);

    floatx4 acc[MF][NF];
#pragma unroll
    for (int i = 0; i < MF; ++i)
#pragma unroll
        for (int j = 0; j < NF; ++j) acc[i][j] = (floatx4){0.f, 0.f, 0.f, 0.f};

    int t = 0;
    for (int k0 = kbeg; k0 < kend; k0 += 32, t ^= 1) {
#pragma unroll
        for (int c = 0; c < CA; ++c) {
            int id = tid + c * 256;
            if (BM * 4 % 256 == 0 || id < BM * 4)
                *(short8*)&As[t][id >> 2][(id & 3) * 8] = ra[c];
        }
#pragma unroll
        for (int c = 0; c < CB; ++c) {
            int id = tid + c * 256;
            if (BN * 4 % 256 == 0 || id < BN * 4)
                *(short8*)&Bs[t][id >> 2][(id & 3) * 8] = rb[c];
        }
        __syncthreads();
        if (k0 + 32 < kend) LOADAB(k0 + 32);

        short8 af[MF], bw[NF];
#pragma unroll
        for (int i = 0; i < MF; ++i)
            af[i] = *(const short8*)&As[t][wm + i * 16 + fr][kq];
#pragma unroll
        for (int j = 0; j < NF; ++j)
            bw[j] = *(const short8*)&Bs[t][wn + j * 16 + fr][kq];
#pragma unroll
        for (int i = 0; i < MF; ++i)
#pragma unroll
            for (int j = 0; j < NF; ++j)
                acc[i][j] = __builtin_amdgcn_mfma_f32_16x16x32_bf16(
                    af[i], bw[j], acc[i][j], 0, 0, 0);
    }
#undef LOADAB

    const int fq = lane >> 4;
#pragma unroll
    for (int i = 0; i < MF; ++i) {
#pragma unroll
        for (int j = 0; j < NF; ++j) {
#pragma unroll
            for (int q = 0; q < 4; ++q) {
                int row = m0 + wm + i * 16 + fq * 4 + q;
                int col = n0 + wn + j * 16 + fr;
                float v = acc[i][j][q];
                if (SPLITK == 1 && bias) v += bias[col];
                if (RELU) v = fmaxf(v, 0.f);
                if (OBF16) Cb[(size_t)row * ldc + col] = cvt_bf16(v);
                else       Cf[(size_t)row * ldc + col] = v;
            }
        }
    }
}

// ---------------- attn + ind_norm fused: hout(bf16) -> x5b rows -------------
__global__ __launch_bounds__(256) void attn_x5(
    const unsigned short* __restrict__ hout,
    const float* __restrict__ tf, const float* __restrict__ im,
    const float* __restrict__ it, const float* __restrict__ fa,
    unsigned short* __restrict__ x5)
{
    const int b = blockIdx.x;
    __shared__ float uo[12][520];
    __shared__ float uw[16][520];
    __shared__ float S[12][16];
    __shared__ float w16[16];
    __shared__ float al[512];

    const int tid = threadIdx.x;
    const int lane = tid & 63;
    const int wid = tid >> 6;
    const unsigned short* hb = hout + (size_t)b * 28 * 512;

    for (int idx = tid; idx < 28 * 64; idx += 256) {
        int n = idx >> 6, c = (idx & 63) * 8;
        short8 v = *(const short8*)(hb + (size_t)n * 512 + c);
        float* row = (n < 12) ? &uo[n][c] : &uw[n - 12][c];
#pragma unroll
        for (int j = 0; j < 8; ++j) row[j] = bf2f((unsigned short)v[j]);
    }
    __syncthreads();

    for (int p = wid; p < 192; p += 4) {
        int i = p >> 4, j = p & 15;
        const float* ua = &uo[i][lane * 8];
        const float* uc = &uw[j][lane * 8];
        float s = 0.f;
#pragma unroll
        for (int d = 0; d < 8; ++d) s += ua[d] * uc[d];
        for (int off = 32; off > 0; off >>= 1) s += __shfl_down(s, off, 64);
        if (lane == 0) S[i][j] = s;
    }
    __syncthreads();

    if (tid < 12) {
        float mx = -1e30f;
        for (int j = 0; j < 16; ++j) mx = fmaxf(mx, S[tid][j]);
        float den = 0.f;
        for (int j = 0; j < 16; ++j) { float p = expf(S[tid][j] - mx); S[tid][j] = p; den += p; }
        float inv = 1.f / den;
        for (int j = 0; j < 16; ++j) S[tid][j] *= inv;
    }
    __syncthreads();

    if (tid < 16) {
        float s = 0.f;
        for (int i = 0; i < 12; ++i) s += S[i][tid];
        w16[tid] = s * (1.f / 12.f);
    }
    __syncthreads();

    for (int d = tid; d < 512; d += 256) {
        float s = 0.f;
#pragma unroll
        for (int j = 0; j < 16; ++j) s += w16[j] * uw[j][d];
        al[d] = s;
    }
    __syncthreads();

    for (int f = wid; f < 5; f += 4) {
        const float* src = (f == 0) ? tf : (f == 1) ? im : (f == 2) ? it : (f == 3) ? fa : nullptr;
        float vals[8];
        float sum = 0.f, sq = 0.f;
#pragma unroll
        for (int j = 0; j < 8; ++j) {
            float v = (f < 4) ? src[(size_t)b * 512 + lane + 64 * j] : al[lane + 64 * j];
            vals[j] = v;
            sum += v;
            sq += v * v;
        }
#pragma unroll
        for (int off = 32; off > 0; off >>= 1) {
            sum += __shfl_xor(sum, off, 64);
            sq  += __shfl_xor(sq,  off, 64);
        }
        float v = (sum != 0.f) ? 1.f : 0.f;
        float nrm = fmaxf(sqrtf(sq + v * v), 1e-12f);
        float inv = 1.f / nrm;
        unsigned short* dst = x5 + ((size_t)b * 5 + f) * 544;
#pragma unroll
        for (int j = 0; j < 8; ++j) dst[lane + 64 * j] = cvt_bf16(vals[j] * inv);
        if (lane == 0) dst[512] = cvt_bf16(v * inv);
        else if (lane < 32) dst[512 + lane] = 0;
    }
}

// ---------------- C2/C4: 5-node complete-graph GAT (bf16 in/out) ------------
template <int RELU>
__global__ __launch_bounds__(256) void g5_gat(
    const unsigned short* __restrict__ Hg,
    const float* __restrict__ asrc, const float* __restrict__ adst,
    const float* __restrict__ bias, unsigned short* __restrict__ outp)
{
    const int b = blockIdx.x;
    __shared__ float ss[5], sd[5];
    __shared__ float alpha[5][5];

    const int tid = threadIdx.x;
    const int lane = tid & 63;
    const int wave = tid >> 6;
    const unsigned short* Hb = Hg + (size_t)b * 5 * 512;

    for (int p = wave; p < 10; p += 4) {
        int n = p >> 1, ty = p & 1;
        const unsigned short* hv = Hb + n * 512;
        const float* av = ty ? adst : asrc;
        float s = 0.f;
#pragma unroll
        for (int j = 0; j < 8; ++j) s += bf2f(hv[lane + 64 * j]) * av[lane + 64 * j];
        for (int off = 32; off > 0; off >>= 1) s += __shfl_down(s, off, 64);
        if (lane == 0) { if (ty) sd[n] = s; else ss[n] = s; }
    }
    __syncthreads();

    if (tid < 5) {
        int dn = tid;
        float e[5];
        float mx = -1e30f;
        for (int s = 0; s < 5; ++s) {
            e[s] = lrelu02(ss[s] + sd[dn]);
            mx = fmaxf(mx, e[s]);
        }
        float den = 0.f;
        for (int s = 0; s < 5; ++s) { e[s] = expf(e[s] - mx); den += e[s]; }
        float inv = 1.f / den;
        for (int s = 0; s < 5; ++s) alpha[dn][s] = e[s] * inv;
    }
    __syncthreads();

    for (int d = tid; d < 512; d += 256) {
        float h0 = bf2f(Hb[0 * 512 + d]), h1 = bf2f(Hb[1 * 512 + d]), h2 = bf2f(Hb[2 * 512 + d]);
        float h3 = bf2f(Hb[3 * 512 + d]), h4 = bf2f(Hb[4 * 512 + d]);
        float bd = bias[d];
#pragma unroll
        for (int dn = 0; dn < 5; ++dn) {
            float v = alpha[dn][0] * h0 + alpha[dn][1] * h1 + alpha[dn][2] * h2 +
                      alpha[dn][3] * h3 + alpha[dn][4] * h4 + bd;
            if (RELU) v = fmaxf(v, 0.f);
            outp[((size_t)b * 5 + dn) * 512 + d] = cvt_bf16(v);
        }
    }
}

// ---------------- final: relu(sum split-K parts + b1) @ m2 + b2 -------------
__global__ __launch_bounds__(64) void final2(
    const float* __restrict__ parts, const float* __restrict__ b1,
    const float* __restrict__ w, const float* __restrict__ bvec,
    float* __restrict__ out)
{
    const int b = blockIdx.x;
    const int lane = threadIdx.x;
    float a0 = 0.f, a1 = 0.f, a2 = 0.f;
#pragma unroll
    for (int j = 0; j < 8; ++j) {
        int d = lane + 64 * j;
        size_t o = (size_t)b * 512 + d;
        float x = parts[o] + parts[262144 + o] + parts[524288 + o] + parts[786432 + o] + b1[d];
        x = fmaxf(x, 0.f);
        a0 += x * w[d * 3 + 0];
        a1 += x * w[d * 3 + 1];
        a2 += x * w[d * 3 + 2];
    }
    for (int off = 32; off > 0; off >>= 1) {
        a0 += __shfl_down(a0, off, 64);
        a1 += __shfl_down(a1, off, 64);
        a2 += __shfl_down(a2, off, 64);
    }
    if (lane == 0) {
        out[b * 3 + 0] = a0 + bvec[0];
        out[b * 3 + 1] = a1 + bvec[1];
        out[b * 3 + 2] = a2 + bvec[2];
    }
}

extern "C" void kernel_launch(void* const* d_in, const int* in_sizes, int n_in,
                              void* d_out, int out_size, void* d_ws, size_t ws_size,
                              hipStream_t stream) {
    const float* text   = (const float*)d_in[0];
    const float* image  = (const float*)d_in[1];
    const float* imgtxt = (const float*)d_in[2];
    const float* face   = (const float*)d_in[3];
    const float* word   = (const float*)d_in[4];
    const float* obj    = (const float*)d_in[5];
    const float* ow_W    = (const float*)d_in[6];
    const float* ow_asrc = (const float*)d_in[7];
    const float* ow_adst = (const float*)d_in[8];
    const float* ow_b    = (const float*)d_in[9];
    const float* g1_W    = (const float*)d_in[10];
    const float* g1_asrc = (const float*)d_in[11];
    const float* g1_adst = (const float*)d_in[12];
    const float* g1_b    = (const float*)d_in[13];
    const float* g2_W    = (const float*)d_in[14];
    const float* g2_asrc = (const float*)d_in[15];
    const float* g2_adst = (const float*)d_in[16];
    const float* g2_b    = (const float*)d_in[17];
    const float* m1_W    = (const float*)d_in[18];
    const float* m1_b    = (const float*)d_in[19];
    const float* m2_W    = (const float*)d_in[20];
    const float* m2_b    = (const float*)d_in[21];

    float* ws = (float*)d_ws;
    float* vg = ws;                                         // 2048 f
    float* hidp = ws + 2048;                                // 4x512x512 f
    unsigned short* owWt = (unsigned short*)(hidp + 1048576); // 512x1024
    unsigned short* g1Wt = owWt + 524288;                   // 512x544
    unsigned short* g2Wt = g1Wt + 278528;                   // 512x512
    unsigned short* m1Wt = g2Wt + 262144;                   // 512x2560
    unsigned short* zcat = m1Wt + 1310720;                  // 14336x1024
    unsigned short* houtb = zcat + 14680064;                // 14336x512
    unsigned short* x5b  = houtb + 7340032;                 // 2560x544
    unsigned short* h1b  = x5b + 1392640;                   // 2560x512
    unsigned short* fsb  = h1b + 1310720;                   // 2560x512
    unsigned short* hgb  = fsb + 1310720;                   // 2560x512

    // prep: vvec + all weight transposes
    prep<<<2448, 256, 0, stream>>>(ow_W, ow_asrc, ow_adst, g1_W, g2_W, m1_W,
                                   vg, owWt, g1Wt, g2Wt, m1Wt);

    // stage A
    ow_pre<<<B_SAMP, 256, 0, stream>>>(word, obj, vg, zcat);
    gemm_glds<<<dim3(112, 4), 256, 0, stream>>>(
        zcat, 1024, owWt, 1024, houtb, 512, 1024, ow_b);
    attn_x5<<<B_SAMP, 256, 0, stream>>>(houtb, text, image, imgtxt, face, x5b);

    // stage C (64x64 tiles, 2x2 wave grid)
    gemm_v3<64, 64, 2, 0, 1, 1><<<dim3(40, 8), 256, 0, stream>>>(
        x5b, 544, g1Wt, 544, hgb, 512, 2560, 512, 544, nullptr);
    g5_gat<1><<<B_SAMP, 256, 0, stream>>>(hgb, g1_asrc, g1_adst, g1_b, h1b);
    gemm_v3<64, 64, 2, 0, 1, 1><<<dim3(40, 8), 256, 0, stream>>>(
        h1b, 512, g2Wt, 512, hgb, 512, 2560, 512, 512, nullptr);
    g5_gat<0><<<B_SAMP, 256, 0, stream>>>(hgb, g2_asrc, g2_adst, g2_b, fsb);

    // stage D (fsb viewed as [512][2560])
    gemm_v3<64, 64, 2, 0, 4, 0><<<dim3(8, 8, 4), 256, 0, stream>>>(
        fsb, 2560, m1Wt, 2560, hidp, 512, 512, 512, 2560, nullptr);
    final2<<<B_SAMP, 64, 0, stream>>>(hidp, m1_b, m2_W, m2_b, (float*)d_out);
}

// Round 10
// 128.567 us; speedup vs baseline: 1.0525x; 1.0164x over previous
//
#include <hip/hip_runtime.h>
#include <hip/hip_bf16.h>
#include <math.h>

// ---------------------------------------------------------------------------
// SentiGAT — round 9: A1 re-gridded for occupancy: 64x128 tile -> 896 blocks
// (3.5/CU), XCD-chunked block swizzle (supergroup = 8 M-tiles x 4 N-tiles,
// 2 MB working set fits XCD L2). glds+linear LDS+dbuf structure kept from r8.
// Everything else identical to round 8.
// ---------------------------------------------------------------------------

#define B_SAMP 512

typedef short short8 __attribute__((ext_vector_type(8)));
typedef float floatx4 __attribute__((ext_vector_type(4)));

__device__ __forceinline__ float lrelu02(float x) { return x > 0.f ? x : 0.2f * x; }

__device__ __forceinline__ unsigned short cvt_bf16(float f) {
    union { float f; unsigned int u; } v; v.f = f;
    unsigned int u = v.u;
    return (unsigned short)((u + 0x7FFFu + ((u >> 16) & 1u)) >> 16);  // RNE
}
__device__ __forceinline__ float bf2f(unsigned short u) {
    union { unsigned int u; float f; } v; v.u = ((unsigned int)u) << 16;
    return v.f;
}
__device__ __forceinline__ void gload_lds16(const unsigned short* g, unsigned short* l) {
    __builtin_amdgcn_global_load_lds(
        (const __attribute__((address_space(1))) void*)g,
        (__attribute__((address_space(3))) void*)l, 16, 0, 0);
}

// ---------------- merged prep: ow_vvec + all weight transposes --------------
__global__ __launch_bounds__(256) void prep(
    const float* __restrict__ ow_W, const float* __restrict__ ow_asrc,
    const float* __restrict__ ow_adst,
    const float* __restrict__ g1_W, const float* __restrict__ g2_W,
    const float* __restrict__ m1_W,
    float* __restrict__ vg, unsigned short* __restrict__ owWt,
    unsigned short* __restrict__ g1Wt, unsigned short* __restrict__ g2Wt,
    unsigned short* __restrict__ m1Wt)
{
    __shared__ float T[32][33];
    const int tid = threadIdx.x;
    int bid = blockIdx.x;

    if (bid < 128) {
        const int lane = tid & 63;
        const int gw = bid * 4 + (tid >> 6);
        for (int idx = gw; idx < 2048; idx += 512) {
            int t = idx >> 9, k = idx & 511;
            const float* a = (t < 2) ? (ow_asrc + t * 512) : (ow_adst + (t - 2) * 512);
            const float* wr = ow_W + (size_t)k * 1024 + (t & 1) * 512;
            float s = 0.f;
#pragma unroll
            for (int j = 0; j < 8; ++j) s += wr[lane + 64 * j] * a[lane + 64 * j];
            for (int off = 32; off > 0; off >>= 1) s += __shfl_down(s, off, 64);
            if (lane == 0) vg[idx] = s;
        }
        return;
    }
    bid -= 128;
    const float* W; int ldw, K, Kpad, koff, ktiles; float scale; unsigned short* Wt;
    if (bid < 256)        { W = ow_W;       ldw = 1024; K = 512;  Kpad = 1024; koff = 0;   scale = 0.5f; Wt = owWt; ktiles = 16; }
    else if (bid < 512)   { bid -= 256;  W = ow_W + 512; ldw = 1024; K = 512;  Kpad = 1024; koff = 512; scale = 0.5f; Wt = owWt; ktiles = 16; }
    else if (bid < 784)   { bid -= 512;  W = g1_W; ldw = 512; K = 513;  Kpad = 544;  koff = 0; scale = 1.f; Wt = g1Wt; ktiles = 17; }
    else if (bid < 1040)  { bid -= 784;  W = g2_W; ldw = 512; K = 512;  Kpad = 512;  koff = 0; scale = 1.f; Wt = g2Wt; ktiles = 16; }
    else                  { bid -= 1040; W = m1_W; ldw = 512; K = 2560; Kpad = 2560; koff = 0; scale = 1.f; Wt = m1Wt; ktiles = 80; }
    const int k0 = (bid % ktiles) * 32;
    const int n0 = (bid / ktiles) * 32;
    {
        int kr = tid >> 3, nc = (tid & 7) * 4;
        float4 v = make_float4(0.f, 0.f, 0.f, 0.f);
        if (k0 + kr < K) v = *(const float4*)(W + (size_t)(k0 + kr) * ldw + n0 + nc);
        T[nc + 0][kr] = v.x * scale; T[nc + 1][kr] = v.y * scale;
        T[nc + 2][kr] = v.z * scale; T[nc + 3][kr] = v.w * scale;
    }
    __syncthreads();
    {
        int nr = tid >> 3, kc = (tid & 7) * 4;
        ushort4 w;
        w.x = cvt_bf16(T[nr][kc + 0]);
        w.y = cvt_bf16(T[nr][kc + 1]);
        w.z = cvt_bf16(T[nr][kc + 2]);
        w.w = cvt_bf16(T[nr][kc + 3]);
        *(ushort4*)(Wt + (size_t)(n0 + nr) * Kpad + koff + k0 + kc) = w;
    }
}

// ---------------- ow_pre: scores + alpha + input-space aggregate ------------
__global__ __launch_bounds__(256) void ow_pre(
    const float* __restrict__ wf, const float* __restrict__ of,
    const float* __restrict__ vg,
    unsigned short* __restrict__ zcat)   // [B*28][1024] bf16
{
    const int b = blockIdx.x;
    __shared__ float Xs[28][512];
    __shared__ float ss[28][2], sd[28][2];
    __shared__ float alpha[16][2][13];

    const int tid = threadIdx.x;
    const int lane = tid & 63;
    const int wid = tid >> 6;

    for (int idx = tid; idx < 28 * 128; idx += 256) {
        int n = idx >> 7, c = (idx & 127) * 4;
        const float* src = (n < 12) ? (wf + ((size_t)b * 12 + n) * 512)
                                    : (of + ((size_t)b * 16 + (n - 12)) * 512);
        *(float4*)&Xs[n][c] = *(const float4*)(src + c);
    }
    __syncthreads();

    for (int p = wid; p < 112; p += 4) {
        int n = p >> 2, t = p & 3;
        const float* vv = vg + t * 512;
        float s = 0.f;
#pragma unroll
        for (int j = 0; j < 8; ++j) s += Xs[n][lane + 64 * j] * vv[lane + 64 * j];
        for (int off = 32; off > 0; off >>= 1) s += __shfl_down(s, off, 64);
        if (lane == 0) { if (t < 2) ss[n][t] = s; else sd[n][t - 2] = s; }
    }
    __syncthreads();

    if (tid < 32) {
        int w = tid >> 1, h = tid & 1;
        float sdv = sd[12 + w][h];
        float e[13], mx = -1e30f;
        for (int j = 0; j < 12; ++j) { e[j] = lrelu02(ss[j][h] + sdv); mx = fmaxf(mx, e[j]); }
        e[12] = lrelu02(ss[12 + w][h] + sdv); mx = fmaxf(mx, e[12]);
        float den = 0.f;
        for (int j = 0; j < 13; ++j) { e[j] = expf(e[j] - mx); den += e[j]; }
        float inv = 1.f / den;
        for (int j = 0; j < 13; ++j) alpha[w][h][j] = e[j] * inv;
    }
    __syncthreads();

    unsigned short* zb = zcat + (size_t)b * 28 * 1024;
    for (int idx = tid; idx < 12 * 1024; idx += 256) {
        int n = idx >> 10, d = idx & 511;
        zb[idx] = cvt_bf16(Xs[n][d]);
    }
    for (int c = tid; c < 1024; c += 256) {
        int h = c >> 9, d = c & 511;
        float xr[12];
#pragma unroll
        for (int j = 0; j < 12; ++j) xr[j] = Xs[j][d];
#pragma unroll 4
        for (int w = 0; w < 16; ++w) {
            float a = alpha[w][h][12] * Xs[12 + w][d];
#pragma unroll
            for (int j = 0; j < 12; ++j) a += alpha[w][h][j] * xr[j];
            zb[(size_t)(12 + w) * 1024 + c] = cvt_bf16(a);
        }
    }
}

// ---------------- A1: glds GEMM, 64x128 tile, XCD-chunked swizzle -----------
// C(bf16) = A(bf16)[M][lda] @ Bt(bf16)[N][ldbt]^T + bias
// BK=32, linear LDS, dbuf, 1 barrier/K-step. 896 blocks (3.5/CU).
__global__ __launch_bounds__(256) void gemm_glds(
    const unsigned short* __restrict__ A, int lda,
    const unsigned short* __restrict__ Bt, int ldbt,
    unsigned short* __restrict__ C, int ldc,
    int K, const float* __restrict__ bias)
{
    __shared__ unsigned short As[2][64][32];
    __shared__ unsigned short Bs[2][128][32];

    const int tid = threadIdx.x;
    const int lane = tid & 63;
    const int wid = tid >> 6;

    // swizzle: supergroup of 32 bids = 8 M-tiles x 4 N-tiles, bid ≡ m (mod 8)
    const int bid = blockIdx.x;
    const int m = (bid >> 5) * 8 + (bid & 7);
    const int n = (bid >> 3) & 3;
    const int m0 = m * 64;
    const int n0 = n * 128;

    // staging: wave wid -> A rows [16w,16w+16) (1 glds), B rows [32w,32w+32) (2 glds)
    const int srow = lane >> 2;        // 0..15
    const int sseg = (lane & 3) * 8;
    const unsigned short* ga = A + (size_t)(m0 + wid * 16 + srow) * lda + sseg;
    const unsigned short* gb = Bt + (size_t)(n0 + wid * 32 + srow) * ldbt + sseg;
    const size_t b16 = (size_t)16 * ldbt;

#define STAGE(t, K0)                                              \
    do {                                                          \
        gload_lds16(ga + (K0), &As[t][wid * 16][0]);              \
        gload_lds16(gb + (K0), &Bs[t][wid * 32][0]);              \
        gload_lds16(gb + (K0) + b16, &Bs[t][wid * 32 + 16][0]);   \
    } while (0)

    const int wm = (wid & 1) * 32;     // 2x2 wave grid: WM=32, WN=64
    const int wn = (wid >> 1) * 64;
    const int fr = lane & 15;
    const int kq = (lane >> 4) * 8;

    floatx4 acc[2][4];
#pragma unroll
    for (int i = 0; i < 2; ++i)
#pragma unroll
        for (int j = 0; j < 4; ++j) acc[i][j] = (floatx4){0.f, 0.f, 0.f, 0.f};

    STAGE(0, 0);
    __syncthreads();   // drains vmcnt: buf0 ready

    int t = 0;
    for (int k0 = 0; k0 < K; k0 += 32, t ^= 1) {
        if (k0 + 32 < K) STAGE(t ^ 1, k0 + 32);   // flies under ds_read+MFMA

        short8 af[2], bw[4];
#pragma unroll
        for (int i = 0; i < 2; ++i)
            af[i] = *(const short8*)&As[t][wm + i * 16 + fr][kq];
#pragma unroll
        for (int j = 0; j < 4; ++j)
            bw[j] = *(const short8*)&Bs[t][wn + j * 16 + fr][kq];
#pragma unroll
        for (int i = 0; i < 2; ++i)
#pragma unroll
            for (int j = 0; j < 4; ++j)
                acc[i][j] = __builtin_amdgcn_mfma_f32_16x16x32_bf16(
                    af[i], bw[j], acc[i][j], 0, 0, 0);
        __syncthreads();   // drains next-tile loads + protects buf swap
    }
#undef STAGE

    const int fq = lane >> 4;
#pragma unroll
    for (int i = 0; i < 2; ++i) {
#pragma unroll
        for (int j = 0; j < 4; ++j) {
#pragma unroll
            for (int q = 0; q < 4; ++q) {
                int row = m0 + wm + i * 16 + fq * 4 + q;
                int col = n0 + wn + j * 16 + fr;
                C[(size_t)row * ldc + col] = cvt_bf16(acc[i][j][q] + bias[col]);
            }
        }
    }
}

// ---------------- GEMM v3: dbuf pipeline (reg-staged), 64x64 ----------------
template <int BM, int BN, int WGM, int RELU, int SPLITK, int OBF16>
__global__ __launch_bounds__(256) void gemm_v3(
    const unsigned short* __restrict__ A, int lda,
    const unsigned short* __restrict__ Bt, int ldbt,
    void* __restrict__ Cv, int ldc,
    int M, int N, int K,
    const float* __restrict__ bias)
{
    constexpr int WGN = 4 / WGM;
    constexpr int WM = BM / WGM, WN = BN / WGN;
    constexpr int MF = WM / 16, NF = WN / 16;
    constexpr int CA = (BM * 4 + 255) / 256, CB = (BN * 4 + 255) / 256;

    __shared__ unsigned short As[2][BM][40];
    __shared__ unsigned short Bs[2][BN][40];

    const int tid = threadIdx.x;
    const int m0 = blockIdx.x * BM;
    const int n0 = blockIdx.y * BN;
    const int lane = tid & 63;
    const int wid = tid >> 6;
    const int wm = (wid % WGM) * WM;
    const int wn = (wid / WGM) * WN;
    const int fr = lane & 15;
    const int kq = (lane >> 4) * 8;

    const int kchunk = K / SPLITK;
    const int kbeg = (SPLITK > 1) ? blockIdx.z * kchunk : 0;
    const int kend = kbeg + kchunk;
    float* Cf = (float*)Cv;
    unsigned short* Cb = (unsigned short*)Cv;
    if (SPLITK > 1) Cf += (size_t)blockIdx.z * M * ldc;

    short8 ra[CA], rb[CB];
#define LOADAB(K0)                                                                       \
    do {                                                                                 \
        _Pragma("unroll")                                                                \
        for (int c = 0; c < CA; ++c) {                                                   \
            int id = tid + c * 256;                                                      \
            if (BM * 4 % 256 == 0 || id < BM * 4)                                        \
                ra[c] = *(const short8*)(A + (size_t)(m0 + (id >> 2)) * lda + (K0) + (id & 3) * 8); \
        }                                                                                \
        _Pragma("unroll")                                                                \
        for (int c = 0; c < CB; ++c) {                                                   \
            int id = tid + c * 256;                                                      \
            if (BN * 4 % 256 == 0 || id < BN * 4)                                        \
                rb[c] = *(const short8*)(Bt + (size_t)(n0 + (id >> 2)) * ldbt + (K0) + (id & 3) * 8); \
        }                                                                                \
    } while (0)

    LOADAB(kbeg);

    floatx4 acc[MF][NF];
#pragma unroll
    for (int i = 0; i < MF; ++i)
#pragma unroll
        for (int j = 0; j < NF; ++j) acc[i][j] = (floatx4){0.f, 0.f, 0.f, 0.f};

    int t = 0;
    for (int k0 = kbeg; k0 < kend; k0 += 32, t ^= 1) {
#pragma unroll
        for (int c = 0; c < CA; ++c) {
            int id = tid + c * 256;
            if (BM * 4 % 256 == 0 || id < BM * 4)
                *(short8*)&As[t][id >> 2][(id & 3) * 8] = ra[c];
        }
#pragma unroll
        for (int c = 0; c < CB; ++c) {
            int id = tid + c * 256;
            if (BN * 4 % 256 == 0 || id < BN * 4)
                *(short8*)&Bs[t][id >> 2][(id & 3) * 8] = rb[c];
        }
        __syncthreads();
        if (k0 + 32 < kend) LOADAB(k0 + 32);

        short8 af[MF], bw[NF];
#pragma unroll
        for (int i = 0; i < MF; ++i)
            af[i] = *(const short8*)&As[t][wm + i * 16 + fr][kq];
#pragma unroll
        for (int j = 0; j < NF; ++j)
            bw[j] = *(const short8*)&Bs[t][wn + j * 16 + fr][kq];
#pragma unroll
        for (int i = 0; i < MF; ++i)
#pragma unroll
            for (int j = 0; j < NF; ++j)
                acc[i][j] = __builtin_amdgcn_mfma_f32_16x16x32_bf16(
                    af[i], bw[j], acc[i][j], 0, 0, 0);
    }
#undef LOADAB

    const int fq = lane >> 4;
#pragma unroll
    for (int i = 0; i < MF; ++i) {
#pragma unroll
        for (int j = 0; j < NF; ++j) {
#pragma unroll
            for (int q = 0; q < 4; ++q) {
                int row = m0 + wm + i * 16 + fq * 4 + q;
                int col = n0 + wn + j * 16 + fr;
                float v = acc[i][j][q];
                if (SPLITK == 1 && bias) v += bias[col];
                if (RELU) v = fmaxf(v, 0.f);
                if (OBF16) Cb[(size_t)row * ldc + col] = cvt_bf16(v);
                else       Cf[(size_t)row * ldc + col] = v;
            }
        }
    }
}

// ---------------- attn + ind_norm fused: hout(bf16) -> x5b rows -------------
__global__ __launch_bounds__(256) void attn_x5(
    const unsigned short* __restrict__ hout,
    const float* __restrict__ tf, const float* __restrict__ im,
    const float* __restrict__ it, const float* __restrict__ fa,
    unsigned short* __restrict__ x5)
{
    const int b = blockIdx.x;
    __shared__ float uo[12][520];
    __shared__ float uw[16][520];
    __shared__ float S[12][16];
    __shared__ float w16[16];
    __shared__ float al[512];

    const int tid = threadIdx.x;
    const int lane = tid & 63;
    const int wid = tid >> 6;
    const unsigned short* hb = hout + (size_t)b * 28 * 512;

    for (int idx = tid; idx < 28 * 64; idx += 256) {
        int n = idx >> 6, c = (idx & 63) * 8;
        short8 v = *(const short8*)(hb + (size_t)n * 512 + c);
        float* row = (n < 12) ? &uo[n][c] : &uw[n - 12][c];
#pragma unroll
        for (int j = 0; j < 8; ++j) row[j] = bf2f((unsigned short)v[j]);
    }
    __syncthreads();

    for (int p = wid; p < 192; p += 4) {
        int i = p >> 4, j = p & 15;
        const float* ua = &uo[i][lane * 8];
        const float* uc = &uw[j][lane * 8];
        float s = 0.f;
#pragma unroll
        for (int d = 0; d < 8; ++d) s += ua[d] * uc[d];
        for (int off = 32; off > 0; off >>= 1) s += __shfl_down(s, off, 64);
        if (lane == 0) S[i][j] = s;
    }
    __syncthreads();

    if (tid < 12) {
        float mx = -1e30f;
        for (int j = 0; j < 16; ++j) mx = fmaxf(mx, S[tid][j]);
        float den = 0.f;
        for (int j = 0; j < 16; ++j) { float p = expf(S[tid][j] - mx); S[tid][j] = p; den += p; }
        float inv = 1.f / den;
        for (int j = 0; j < 16; ++j) S[tid][j] *= inv;
    }
    __syncthreads();

    if (tid < 16) {
        float s = 0.f;
        for (int i = 0; i < 12; ++i) s += S[i][tid];
        w16[tid] = s * (1.f / 12.f);
    }
    __syncthreads();

    for (int d = tid; d < 512; d += 256) {
        float s = 0.f;
#pragma unroll
        for (int j = 0; j < 16; ++j) s += w16[j] * uw[j][d];
        al[d] = s;
    }
    __syncthreads();

    for (int f = wid; f < 5; f += 4) {
        const float* src = (f == 0) ? tf : (f == 1) ? im : (f == 2) ? it : (f == 3) ? fa : nullptr;
        float vals[8];
        float sum = 0.f, sq = 0.f;
#pragma unroll
        for (int j = 0; j < 8; ++j) {
            float v = (f < 4) ? src[(size_t)b * 512 + lane + 64 * j] : al[lane + 64 * j];
            vals[j] = v;
            sum += v;
            sq += v * v;
        }
#pragma unroll
        for (int off = 32; off > 0; off >>= 1) {
            sum += __shfl_xor(sum, off, 64);
            sq  += __shfl_xor(sq,  off, 64);
        }
        float v = (sum != 0.f) ? 1.f : 0.f;
        float nrm = fmaxf(sqrtf(sq + v * v), 1e-12f);
        float inv = 1.f / nrm;
        unsigned short* dst = x5 + ((size_t)b * 5 + f) * 544;
#pragma unroll
        for (int j = 0; j < 8; ++j) dst[lane + 64 * j] = cvt_bf16(vals[j] * inv);
        if (lane == 0) dst[512] = cvt_bf16(v * inv);
        else if (lane < 32) dst[512 + lane] = 0;
    }
}

// ---------------- C2/C4: 5-node complete-graph GAT (bf16 in/out) ------------
template <int RELU>
__global__ __launch_bounds__(256) void g5_gat(
    const unsigned short* __restrict__ Hg,
    const float* __restrict__ asrc, const float* __restrict__ adst,
    const float* __restrict__ bias, unsigned short* __restrict__ outp)
{
    const int b = blockIdx.x;
    __shared__ float ss[5], sd[5];
    __shared__ float alpha[5][5];

    const int tid = threadIdx.x;
    const int lane = tid & 63;
    const int wave = tid >> 6;
    const unsigned short* Hb = Hg + (size_t)b * 5 * 512;

    for (int p = wave; p < 10; p += 4) {
        int n = p >> 1, ty = p & 1;
        const unsigned short* hv = Hb + n * 512;
        const float* av = ty ? adst : asrc;
        float s = 0.f;
#pragma unroll
        for (int j = 0; j < 8; ++j) s += bf2f(hv[lane + 64 * j]) * av[lane + 64 * j];
        for (int off = 32; off > 0; off >>= 1) s += __shfl_down(s, off, 64);
        if (lane == 0) { if (ty) sd[n] = s; else ss[n] = s; }
    }
    __syncthreads();

    if (tid < 5) {
        int dn = tid;
        float e[5];
        float mx = -1e30f;
        for (int s = 0; s < 5; ++s) {
            e[s] = lrelu02(ss[s] + sd[dn]);
            mx = fmaxf(mx, e[s]);
        }
        float den = 0.f;
        for (int s = 0; s < 5; ++s) { e[s] = expf(e[s] - mx); den += e[s]; }
        float inv = 1.f / den;
        for (int s = 0; s < 5; ++s) alpha[dn][s] = e[s] * inv;
    }
    __syncthreads();

    for (int d = tid; d < 512; d += 256) {
        float h0 = bf2f(Hb[0 * 512 + d]), h1 = bf2f(Hb[1 * 512 + d]), h2 = bf2f(Hb[2 * 512 + d]);
        float h3 = bf2f(Hb[3 * 512 + d]), h4 = bf2f(Hb[4 * 512 + d]);
        float bd = bias[d];
#pragma unroll
        for (int dn = 0; dn < 5; ++dn) {
            float v = alpha[dn][0] * h0 + alpha[dn][1] * h1 + alpha[dn][2] * h2 +
                      alpha[dn][3] * h3 + alpha[dn][4] * h4 + bd;
            if (RELU) v = fmaxf(v, 0.f);
            outp[((size_t)b * 5 + dn) * 512 + d] = cvt_bf16(v);
        }
    }
}

// ---------------- final: relu(sum split-K parts + b1) @ m2 + b2 -------------
__global__ __launch_bounds__(64) void final2(
    const float* __restrict__ parts, const float* __restrict__ b1,
    const float* __restrict__ w, const float* __restrict__ bvec,
    float* __restrict__ out)
{
    const int b = blockIdx.x;
    const int lane = threadIdx.x;
    float a0 = 0.f, a1 = 0.f, a2 = 0.f;
#pragma unroll
    for (int j = 0; j < 8; ++j) {
        int d = lane + 64 * j;
        size_t o = (size_t)b * 512 + d;
        float x = parts[o] + parts[262144 + o] + parts[524288 + o] + parts[786432 + o] + b1[d];
        x = fmaxf(x, 0.f);
        a0 += x * w[d * 3 + 0];
        a1 += x * w[d * 3 + 1];
        a2 += x * w[d * 3 + 2];
    }
    for (int off = 32; off > 0; off >>= 1) {
        a0 += __shfl_down(a0, off, 64);
        a1 += __shfl_down(a1, off, 64);
        a2 += __shfl_down(a2, off, 64);
    }
    if (lane == 0) {
        out[b * 3 + 0] = a0 + bvec[0];
        out[b * 3 + 1] = a1 + bvec[1];
        out[b * 3 + 2] = a2 + bvec[2];
    }
}

extern "C" void kernel_launch(void* const* d_in, const int* in_sizes, int n_in,
                              void* d_out, int out_size, void* d_ws, size_t ws_size,
                              hipStream_t stream) {
    const float* text   = (const float*)d_in[0];
    const float* image  = (const float*)d_in[1];
    const float* imgtxt = (const float*)d_in[2];
    const float* face   = (const float*)d_in[3];
    const float* word   = (const float*)d_in[4];
    const float* obj    = (const float*)d_in[5];
    const float* ow_W    = (const float*)d_in[6];
    const float* ow_asrc = (const float*)d_in[7];
    const float* ow_adst = (const float*)d_in[8];
    const float* ow_b    = (const float*)d_in[9];
    const float* g1_W    = (const float*)d_in[10];
    const float* g1_asrc = (const float*)d_in[11];
    const float* g1_adst = (const float*)d_in[12];
    const float* g1_b    = (const float*)d_in[13];
    const float* g2_W    = (const float*)d_in[14];
    const float* g2_asrc = (const float*)d_in[15];
    const float* g2_adst = (const float*)d_in[16];
    const float* g2_b    = (const float*)d_in[17];
    const float* m1_W    = (const float*)d_in[18];
    const float* m1_b    = (const float*)d_in[19];
    const float* m2_W    = (const float*)d_in[20];
    const float* m2_b    = (const float*)d_in[21];

    float* ws = (float*)d_ws;
    float* vg = ws;                                         // 2048 f
    float* hidp = ws + 2048;                                // 4x512x512 f
    unsigned short* owWt = (unsigned short*)(hidp + 1048576); // 512x1024
    unsigned short* g1Wt = owWt + 524288;                   // 512x544
    unsigned short* g2Wt = g1Wt + 278528;                   // 512x512
    unsigned short* m1Wt = g2Wt + 262144;                   // 512x2560
    unsigned short* zcat = m1Wt + 1310720;                  // 14336x1024
    unsigned short* houtb = zcat + 14680064;                // 14336x512
    unsigned short* x5b  = houtb + 7340032;                 // 2560x544
    unsigned short* h1b  = x5b + 1392640;                   // 2560x512
    unsigned short* fsb  = h1b + 1310720;                   // 2560x512
    unsigned short* hgb  = fsb + 1310720;                   // 2560x512

    // prep: vvec + all weight transposes
    prep<<<2448, 256, 0, stream>>>(ow_W, ow_asrc, ow_adst, g1_W, g2_W, m1_W,
                                   vg, owWt, g1Wt, g2Wt, m1Wt);

    // stage A
    ow_pre<<<B_SAMP, 256, 0, stream>>>(word, obj, vg, zcat);
    gemm_glds<<<896, 256, 0, stream>>>(
        zcat, 1024, owWt, 1024, houtb, 512, 1024, ow_b);
    attn_x5<<<B_SAMP, 256, 0, stream>>>(houtb, text, image, imgtxt, face, x5b);

    // stage C (64x64 tiles, 2x2 wave grid)
    gemm_v3<64, 64, 2, 0, 1, 1><<<dim3(40, 8), 256, 0, stream>>>(
        x5b, 544, g1Wt, 544, hgb, 512, 2560, 512, 544, nullptr);
    g5_gat<1><<<B_SAMP, 256, 0, stream>>>(hgb, g1_asrc, g1_adst, g1_b, h1b);
    gemm_v3<64, 64, 2, 0, 1, 1><<<dim3(40, 8), 256, 0, stream>>>(
        h1b, 512, g2Wt, 512, hgb, 512, 2560, 512, 512, nullptr);
    g5_gat<0><<<B_SAMP, 256, 0, stream>>>(hgb, g2_asrc, g2_adst, g2_b, fsb);

    // stage D (fsb viewed as [512][2560])
    gemm_v3<64, 64, 2, 0, 4, 0><<<dim3(8, 8, 4), 256, 0, stream>>>(
        fsb, 2560, m1Wt, 2560, hidp, 512, 512, 512, 2560, nullptr);
    final2<<<B_SAMP, 64, 0, stream>>>(hidp, m1_b, m2_W, m2_b, (float*)d_out);
}